// Round 1
// baseline (12882.498 us; speedup 1.0000x reference)
//
#include <hip/hip_runtime.h>
#include <hip/hip_bf16.h>

// Sizes (fixed by the problem)
#define B_   256
#define E_   256
#define H_   256
#define T_   512
#define OUT_ 702
#define G4H  1024   // 4*H

typedef _Float16 half8 __attribute__((ext_vector_type(8)));
typedef float    floatx4 __attribute__((ext_vector_type(4)));
typedef unsigned long long ull;

// Workspace layout (bytes). Total ~69.3 MB.
#define OFF_FLAGS  0          // 256 ints (group-member step flags)
#define OFF_DTF    2048       // 1 int dtype flag (0=f32 inputs, 1=bf16 inputs)
#define OFF_HBUF   4096       // 2 * 16 groups * 16 rows * 256 cols * fp16 = 262144
#define OFF_BASE   266240     // 256*1024 fp32 = 1 MB
#define OFF_WC16   1314816    // 1024*256 fp16 = 512 KB  (W_ih + W_hh)
#define OFF_WREC16 1839104    // 704*256 fp16 (zero-padded rows 702..703)
#define OFF_HS16   2199552    // 256*512*256 fp16 = 64 MB (hs in projection layout)

__device__ __forceinline__ float ldin(const void* p, long i, int bf) {
  return bf ? __bfloat162float(((const __hip_bfloat16*)p)[i]) : ((const float*)p)[i];
}
__device__ __forceinline__ void stout(void* p, long i, float v, int bf) {
  if (bf) ((__hip_bfloat16*)p)[i] = __float2bfloat16(v);
  else    ((float*)p)[i] = v;
}
__device__ __forceinline__ float sigf(float x)  { return 1.0f / (1.0f + __expf(-x)); }
__device__ __forceinline__ float tanh_(float x) { float e = __expf(2.0f * x); return 1.0f - 2.0f / (e + 1.0f); }

// ---------------------------------------------------------------------------
// K0: runtime input-dtype detection. If the buffer holds bf16 pairs, the low 16
// bits of each fp32-read word are a bf16 of ~N(0,1): its exponent field
// ((u>>7)&0xFF) clusters in [100,129]. For true fp32, those bits are uniform
// low-mantissa bits (~12% in range). 256 samples, threshold 128.
__global__ void k_detect(const unsigned int* emb, int* dtf) {
  int tid = threadIdx.x;
  int cnt = 0;
  for (int i = tid; i < 256; i += 64) {
    unsigned int u = emb[i];
    unsigned int e = (u >> 7) & 0xFF;
    cnt += (e >= 100 && e <= 129) ? 1 : 0;
  }
  for (int off = 32; off > 0; off >>= 1) cnt += __shfl_down(cnt, off);
  if (tid == 0) *dtf = (cnt >= 128) ? 1 : 0;
}

// K1: W_comb = W_ih + W_hh -> fp16  [1024][256]
__global__ void k_prep_wc(const void* wih, const void* whh, _Float16* wc, const int* dtf) {
  int bf = *dtf;
  long i = (long)blockIdx.x * 256 + threadIdx.x;
  wc[i] = (_Float16)(ldin(wih, i, bf) + ldin(whh, i, bf));
}

// K1b: W_rec -> fp16, padded to [704][256] with zeros
__global__ void k_prep_wrec(const void* wrec, _Float16* wr, const int* dtf) {
  int bf = *dtf;
  long i = (long)blockIdx.x * 256 + threadIdx.x;   // < 704*256
  wr[i] = (i < (long)OUT_ * H_) ? (_Float16)ldin(wrec, i, bf) : (_Float16)0.0f;
}

// K2: base[b][n] = x0[b]·W_ih[n] + b_ih[n] + b_hh[n]   (fp32, exact)
__global__ void k_prep_base(const void* emb, const void* wih, const void* bih,
                            const void* bhh, float* base, const int* dtf) {
  int bf = *dtf;
  int b = blockIdx.x >> 2;
  int n = (blockIdx.x & 3) * 256 + threadIdx.x;
  __shared__ float x0s[256];
  x0s[threadIdx.x] = ldin(emb, (long)b * E_ + threadIdx.x, bf);
  __syncthreads();
  float acc = ldin(bih, n, bf) + ldin(bhh, n, bf);
  const long wrow = (long)n * E_;
  for (int k = 0; k < E_; ++k) acc += x0s[k] * ldin(wih, wrow + k, bf);
  base[(long)b * G4H + n] = acc;
}

// ---------------------------------------------------------------------------
// K3: persistent LSTM recurrence.
// Grid: 256 blocks x 256 threads. group g = blockIdx>>4 owns batch rows
// [16g,16g+16); member m = blockIdx&15 owns hidden cols [16m,16m+16).
// W_comb slice (4 gate types x 16 cols x 256 K, fp16) lives in registers as
// MFMA B-fragments (32 VGPR), loaded once. Wave w computes gate type w:
// D[16x64] = h[16x256] @ Wslice^T via 8-chain mfma_f32_16x16x32_f16.
// h exchanged between the 16 member blocks via agent-scope atomics + flags.
__global__ void __launch_bounds__(256) k_lstm(char* ws, void* dout, const int* dtf) {
  const int bf  = *dtf;
  const int tid = threadIdx.x;
  const int g   = blockIdx.x >> 4;
  const int mem = blockIdx.x & 15;
  const int wid = tid >> 6;
  const int lane = tid & 63;
  const int q = lane >> 4;
  const int r = lane & 15;

  _Float16* wc   = (_Float16*)(ws + OFF_WC16);
  float*    base = (float*)(ws + OFF_BASE);
  ull*      hbuf = (ull*)(ws + OFF_HBUF);
  int*      flags = (int*)(ws + OFF_FLAGS);
  _Float16* hs16 = (_Float16*)(ws + OFF_HS16);

  // B-fragments: lane holds Wc[n = wid*256 + mem*16 + r][kb*32 + q*8 .. +8]
  half8 wfrag[8];
  {
    const long wrow = (long)(wid * 256 + mem * 16 + r) * H_;
#pragma unroll
    for (int kb = 0; kb < 8; ++kb)
      wfrag[kb] = *(const half8*)(wc + wrow + kb * 32 + q * 8);
  }

  const int m  = tid >> 4;   // local batch row for pointwise phase
  const int jl = tid & 15;   // local hidden col
  float basev[4];
  {
    const long brow = (long)(g * 16 + m) * G4H + mem * 16 + jl;
#pragma unroll
    for (int ty = 0; ty < 4; ++ty) basev[ty] = base[brow + ty * 256];
  }

  __shared__ _Float16 h_lds[16][264];    // 16 rows x 256 cols (+16B pad)
  __shared__ float gates_lds[16][68];    // [m][ty*16+jl]
  for (int i = tid; i < 16 * 264; i += 256) (&h_lds[0][0])[i] = (_Float16)0.0f;
  float c = 0.0f;
  __syncthreads();

  const long out2off = (long)B_ * T_ * OUT_;
  const long orow_base = ((long)(g * 16 + m) * T_) * H_ + mem * 16 + jl;

  for (int t = 0; t < T_; ++t) {
    // gates(own 64 cols) = h_prev @ Wslice^T  (t=0: h_prev = 0 -> gates = base)
    floatx4 acc = {0.f, 0.f, 0.f, 0.f};
#pragma unroll
    for (int kb = 0; kb < 8; ++kb) {
      half8 a = *(const half8*)(&h_lds[r][kb * 32 + q * 8]);
      acc = __builtin_amdgcn_mfma_f32_16x16x32_f16(a, wfrag[kb], acc, 0, 0, 0);
    }
#pragma unroll
    for (int e = 0; e < 4; ++e) gates_lds[q * 4 + e][wid * 16 + r] = acc[e];
    __syncthreads();

    float gi = gates_lds[m][jl]      + basev[0];
    float gf = gates_lds[m][16 + jl] + basev[1];
    float gg = gates_lds[m][32 + jl] + basev[2];
    float go = gates_lds[m][48 + jl] + basev[3];
    c = sigf(gf) * c + sigf(gi) * tanh_(gg);
    float h = sigf(go) * tanh_(c);
    h_lds[m][mem * 16 + jl] = (_Float16)h;
    __syncthreads();

    if (t < T_ - 1) {
      const int par = t & 1;
      // publish own 16x16 fp16 slice (write-through to LLC)
      if (tid < 64) {
        int pm = tid >> 2, pu = tid & 3;
        ull v = *(const ull*)(&h_lds[pm][mem * 16 + pu * 4]);
        __hip_atomic_store(&hbuf[((long)(par * 16 + g) * 16 + pm) * 64 + mem * 4 + pu],
                           v, __ATOMIC_RELAXED, __HIP_MEMORY_SCOPE_AGENT);
      }
      __threadfence();
      __syncthreads();
      if (tid == 0)
        __hip_atomic_store(&flags[g * 16 + mem], t + 1,
                           __ATOMIC_RELEASE, __HIP_MEMORY_SCOPE_AGENT);
    }

    // stream outputs while peers catch up (register h only)
    stout(dout, out2off + orow_base + (long)t * H_, h, bf);
    hs16[orow_base + (long)t * H_] = (_Float16)h;

    if (t < T_ - 1) {
      const int par = t & 1;
      if (tid < 16) {
        int it = 0;
        while (__hip_atomic_load(&flags[g * 16 + tid], __ATOMIC_ACQUIRE,
                                 __HIP_MEMORY_SCOPE_AGENT) < t + 1) {
          __builtin_amdgcn_s_sleep(1);
          if (++it > 100000000) break;   // safety: wrong > hung
        }
      }
      __syncthreads();
      // gather full h_t (16 rows x 256 cols) into LDS for next step
#pragma unroll
      for (int i2 = 0; i2 < 4; ++i2) {
        int flat = tid * 4 + i2;
        int pm = flat >> 6, cu = flat & 63;
        ull v = __hip_atomic_load(&hbuf[((long)(par * 16 + g) * 16 + pm) * 64 + cu],
                                  __ATOMIC_RELAXED, __HIP_MEMORY_SCOPE_AGENT);
        *(ull*)(&h_lds[pm][cu * 4]) = v;
      }
      __syncthreads();
    }
  }
}

// ---------------------------------------------------------------------------
// K4: projection  out1[M=131072][702] = hs16[M][256] @ Wrec16^T + b_rec
// Grid 8192 = 2048 M-blocks (tile 64) x 4 N-blocks (tile 192). Wave w handles
// n-tiles {3w..3w+2}; B-fragments in registers, A staged in LDS.
__global__ void __launch_bounds__(256) k_proj(const char* ws, const void* brec,
                                              void* dout, const int* dtf) {
  const int bf  = *dtf;
  const int tid = threadIdx.x;
  const int wid = tid >> 6, lane = tid & 63, q = lane >> 4, r = lane & 15;
  const int mb = blockIdx.x & 2047, nb = blockIdx.x >> 11;
  const long mbase = (long)mb * 64;
  const int  nbase = nb * 192;
  const _Float16* hs16 = (const _Float16*)(ws + OFF_HS16);
  const _Float16* wr16 = (const _Float16*)(ws + OFF_WREC16);

  __shared__ _Float16 a_lds[64][264];
#pragma unroll
  for (int i = 0; i < 8; ++i) {
    int u = tid + i * 256;              // 2048 units of 8 halves
    int row = u >> 5, c8 = (u & 31) * 8;
    half8 v = *(const half8*)(hs16 + (mbase + row) * H_ + c8);
    *(half8*)(&a_lds[row][c8]) = v;
  }
  __syncthreads();

  half8 bfrag[3][8];
  float bias[3];
#pragma unroll
  for (int j = 0; j < 3; ++j) {
    int ncol = nbase + (wid * 3 + j) * 16 + r;
    bias[j] = 0.0f;
    if (ncol < 704) {
      const long wrow = (long)ncol * H_;
#pragma unroll
      for (int kb = 0; kb < 8; ++kb)
        bfrag[j][kb] = *(const half8*)(wr16 + wrow + kb * 32 + q * 8);
    } else {
      half8 z = {0, 0, 0, 0, 0, 0, 0, 0};
#pragma unroll
      for (int kb = 0; kb < 8; ++kb) bfrag[j][kb] = z;
    }
    if (ncol < OUT_) bias[j] = ldin(brec, ncol, bf);
  }

  floatx4 acc[3][4];
#pragma unroll
  for (int j = 0; j < 3; ++j)
#pragma unroll
    for (int ms = 0; ms < 4; ++ms) acc[j][ms] = (floatx4){0.f, 0.f, 0.f, 0.f};

#pragma unroll
  for (int ms = 0; ms < 4; ++ms) {
#pragma unroll
    for (int kb = 0; kb < 8; ++kb) {
      half8 a = *(const half8*)(&a_lds[ms * 16 + r][kb * 32 + q * 8]);
#pragma unroll
      for (int j = 0; j < 3; ++j)
        acc[j][ms] = __builtin_amdgcn_mfma_f32_16x16x32_f16(a, bfrag[j][kb], acc[j][ms], 0, 0, 0);
    }
  }

#pragma unroll
  for (int j = 0; j < 3; ++j) {
    int ncol = nbase + (wid * 3 + j) * 16 + r;
    if (ncol >= OUT_) continue;
#pragma unroll
    for (int ms = 0; ms < 4; ++ms) {
#pragma unroll
      for (int e = 0; e < 4; ++e) {
        long mrow = mbase + ms * 16 + q * 4 + e;
        stout(dout, mrow * (long)OUT_ + ncol, acc[j][ms][e] + bias[j], bf);
      }
    }
  }
}

// ---------------------------------------------------------------------------
extern "C" void kernel_launch(void* const* d_in, const int* in_sizes, int n_in,
                              void* d_out, int out_size, void* d_ws, size_t ws_size,
                              hipStream_t stream) {
  const void* embed = d_in[0];
  const void* W_ih  = d_in[1];
  const void* W_hh  = d_in[2];
  const void* b_ih  = d_in[3];
  const void* b_hh  = d_in[4];
  const void* W_rec = d_in[5];
  const void* b_rec = d_in[6];
  char* ws = (char*)d_ws;
  const int* dtf = (const int*)(ws + OFF_DTF);

  // zero sync flags (+dtf slot) every launch — replay-safe
  hipMemsetAsync(ws, 0, 4096, stream);
  k_detect<<<1, 64, 0, stream>>>((const unsigned int*)embed, (int*)(ws + OFF_DTF));
  k_prep_wc<<<1024, 256, 0, stream>>>(W_ih, W_hh, (_Float16*)(ws + OFF_WC16), dtf);
  k_prep_wrec<<<704, 256, 0, stream>>>(W_rec, (_Float16*)(ws + OFF_WREC16), dtf);
  k_prep_base<<<1024, 256, 0, stream>>>(embed, W_ih, b_ih, b_hh, (float*)(ws + OFF_BASE), dtf);
  k_lstm<<<256, 256, 0, stream>>>(ws, d_out, dtf);
  k_proj<<<8192, 256, 0, stream>>>(ws, b_rec, d_out, dtf);
}

// Round 2
// 2433.592 us; speedup vs baseline: 5.2936x; 5.2936x over previous
//
#include <hip/hip_runtime.h>
#include <hip/hip_bf16.h>

// Sizes (fixed by the problem)
#define B_   256
#define E_   256
#define H_   256
#define T_   512
#define OUT_ 702
#define G4H  1024   // 4*H

typedef _Float16 half8 __attribute__((ext_vector_type(8)));
typedef float    floatx4 __attribute__((ext_vector_type(4)));
typedef unsigned long long ull;

// Workspace layout (bytes). Total ~69.3 MB.
#define OFF_FLAGS  0          // 256 ints (group-member step flags)
#define OFF_DTF    2048       // 1 int dtype flag (0=f32 inputs, 1=bf16 inputs)
#define OFF_HBUF   4096       // 2 * 16 groups * 16 rows * 256 cols * fp16 = 262144
#define OFF_BASE   266240     // 256*1024 fp32 = 1 MB
#define OFF_WC16   1314816    // 1024*256 fp16 = 512 KB  (W_ih + W_hh)
#define OFF_WREC16 1839104    // 704*256 fp16 (zero-padded rows 702..703)
#define OFF_HS16   2199552    // 256*512*256 fp16 = 64 MB (hs in projection layout)

__device__ __forceinline__ float ldin(const void* p, long i, int bf) {
  return bf ? __bfloat162float(((const __hip_bfloat16*)p)[i]) : ((const float*)p)[i];
}
__device__ __forceinline__ void stout(void* p, long i, float v, int bf) {
  if (bf) ((__hip_bfloat16*)p)[i] = __float2bfloat16(v);
  else    ((float*)p)[i] = v;
}
__device__ __forceinline__ float sigf(float x)  { return 1.0f / (1.0f + __expf(-x)); }
__device__ __forceinline__ float tanh_(float x) { float e = __expf(2.0f * x); return 1.0f - 2.0f / (e + 1.0f); }

// ---------------------------------------------------------------------------
// K0: runtime input-dtype detection (bf16-pair vs fp32 heuristic on exponent
// field of low 16 bits). Kept from R1 (passed).
__global__ void k_detect(const unsigned int* emb, int* dtf) {
  int tid = threadIdx.x;
  int cnt = 0;
  for (int i = tid; i < 256; i += 64) {
    unsigned int u = emb[i];
    unsigned int e = (u >> 7) & 0xFF;
    cnt += (e >= 100 && e <= 129) ? 1 : 0;
  }
  for (int off = 32; off > 0; off >>= 1) cnt += __shfl_down(cnt, off);
  if (tid == 0) *dtf = (cnt >= 128) ? 1 : 0;
}

// K1: W_comb = W_ih + W_hh -> fp16  [1024][256]
__global__ void k_prep_wc(const void* wih, const void* whh, _Float16* wc, const int* dtf) {
  int bf = *dtf;
  long i = (long)blockIdx.x * 256 + threadIdx.x;
  wc[i] = (_Float16)(ldin(wih, i, bf) + ldin(whh, i, bf));
}

// K1b: W_rec -> fp16, padded to [704][256] with zeros
__global__ void k_prep_wrec(const void* wrec, _Float16* wr, const int* dtf) {
  int bf = *dtf;
  long i = (long)blockIdx.x * 256 + threadIdx.x;   // < 704*256
  wr[i] = (i < (long)OUT_ * H_) ? (_Float16)ldin(wrec, i, bf) : (_Float16)0.0f;
}

// K2: base[b][n] = x0[b]·W_ih[n] + b_ih[n] + b_hh[n]   (fp32, exact)
__global__ void k_prep_base(const void* emb, const void* wih, const void* bih,
                            const void* bhh, float* base, const int* dtf) {
  int bf = *dtf;
  int b = blockIdx.x >> 2;
  int n = (blockIdx.x & 3) * 256 + threadIdx.x;
  __shared__ float x0s[256];
  x0s[threadIdx.x] = ldin(emb, (long)b * E_ + threadIdx.x, bf);
  __syncthreads();
  float acc = ldin(bih, n, bf) + ldin(bhh, n, bf);
  const long wrow = (long)n * E_;
  for (int k = 0; k < E_; ++k) acc += x0s[k] * ldin(wih, wrow + k, bf);
  base[(long)b * G4H + n] = acc;
}

// ---------------------------------------------------------------------------
// K3: persistent LSTM recurrence.
// Grid: 256 blocks x 256 threads. group g = blockIdx>>4 owns batch rows
// [16g,16g+16); member m = blockIdx&15 owns hidden cols [16m,16m+16).
// Cross-block h-exchange: ALL communicated data moves via RELAXED agent-scope
// atomics (sc0|sc1 -> serialize at memory-side LLC, bypassing non-coherent
// per-XCD L2). R1 post-mortem: ACQUIRE polls emitted buffer_inv (full-L2
// invalidate per iteration) and __threadfence emitted buffer_wbl2 (full-L2
// writeback per step) -> 26 us/step cache-maintenance storm. Replaced with:
//   publish(relaxed) -> s_waitcnt vmcnt(0) -> flag(relaxed)   [no wbl2]
//   poll(relaxed) -> syncthreads -> gather(relaxed)           [no inv]
__global__ void __launch_bounds__(256) k_lstm(char* ws, void* dout, const int* dtf) {
  const int bf  = *dtf;
  const int tid = threadIdx.x;
  const int g   = blockIdx.x >> 4;
  const int mem = blockIdx.x & 15;
  const int wid = tid >> 6;
  const int lane = tid & 63;
  const int q = lane >> 4;
  const int r = lane & 15;

  _Float16* wc   = (_Float16*)(ws + OFF_WC16);
  float*    base = (float*)(ws + OFF_BASE);
  ull*      hbuf = (ull*)(ws + OFF_HBUF);
  int*      flags = (int*)(ws + OFF_FLAGS);
  _Float16* hs16 = (_Float16*)(ws + OFF_HS16);

  // B-fragments: lane holds Wc[n = wid*256 + mem*16 + r][kb*32 + q*8 .. +8]
  half8 wfrag[8];
  {
    const long wrow = (long)(wid * 256 + mem * 16 + r) * H_;
#pragma unroll
    for (int kb = 0; kb < 8; ++kb)
      wfrag[kb] = *(const half8*)(wc + wrow + kb * 32 + q * 8);
  }

  const int m  = tid >> 4;   // local batch row for pointwise phase
  const int jl = tid & 15;   // local hidden col
  float basev[4];
  {
    const long brow = (long)(g * 16 + m) * G4H + mem * 16 + jl;
#pragma unroll
    for (int ty = 0; ty < 4; ++ty) basev[ty] = base[brow + ty * 256];
  }

  __shared__ _Float16 h_lds[16][264];    // 16 rows x 256 cols (+16B pad)
  __shared__ float gates_lds[16][68];    // [m][ty*16+jl]
  for (int i = tid; i < 16 * 264; i += 256) (&h_lds[0][0])[i] = (_Float16)0.0f;
  float c = 0.0f;
  __syncthreads();

  const long out2off = (long)B_ * T_ * OUT_;
  const long orow_base = ((long)(g * 16 + m) * T_) * H_ + mem * 16 + jl;

  for (int t = 0; t < T_; ++t) {
    // gates(own 64 cols) = h_prev @ Wslice^T  (t=0: h_prev = 0 -> gates = base)
    floatx4 acc = {0.f, 0.f, 0.f, 0.f};
#pragma unroll
    for (int kb = 0; kb < 8; ++kb) {
      half8 a = *(const half8*)(&h_lds[r][kb * 32 + q * 8]);
      acc = __builtin_amdgcn_mfma_f32_16x16x32_f16(a, wfrag[kb], acc, 0, 0, 0);
    }
#pragma unroll
    for (int e = 0; e < 4; ++e) gates_lds[q * 4 + e][wid * 16 + r] = acc[e];
    __syncthreads();

    float gi = gates_lds[m][jl]      + basev[0];
    float gf = gates_lds[m][16 + jl] + basev[1];
    float gg = gates_lds[m][32 + jl] + basev[2];
    float go = gates_lds[m][48 + jl] + basev[3];
    c = sigf(gf) * c + sigf(gi) * tanh_(gg);
    float h = sigf(go) * tanh_(c);
    h_lds[m][mem * 16 + jl] = (_Float16)h;
    __syncthreads();

    if (t < T_ - 1) {
      const int par = t & 1;
      // publish own 16x16 fp16 slice straight to LLC (wave 0 only),
      // wait for retirement, then raise flag — all relaxed, no wbl2/inv.
      if (wid == 0) {
        int pm = lane >> 2, pu = lane & 3;
        ull v = *(const ull*)(&h_lds[pm][mem * 16 + pu * 4]);
        __hip_atomic_store(&hbuf[((long)(par * 16 + g) * 16 + pm) * 64 + mem * 4 + pu],
                           v, __ATOMIC_RELAXED, __HIP_MEMORY_SCOPE_AGENT);
        asm volatile("s_waitcnt vmcnt(0)" ::: "memory");
        if (lane == 0)
          __hip_atomic_store(&flags[g * 16 + mem], t + 1,
                             __ATOMIC_RELAXED, __HIP_MEMORY_SCOPE_AGENT);
      }
    }

    // stream outputs while peers catch up (register h only)
    stout(dout, out2off + orow_base + (long)t * H_, h, bf);
    hs16[orow_base + (long)t * H_] = (_Float16)h;

    if (t < T_ - 1) {
      const int par = t & 1;
      if (tid < 16) {
        int it = 0;
        while (__hip_atomic_load(&flags[g * 16 + tid], __ATOMIC_RELAXED,
                                 __HIP_MEMORY_SCOPE_AGENT) < t + 1) {
          __builtin_amdgcn_s_sleep(1);
          if (++it > 100000000) break;   // safety: wrong > hung
        }
      }
      __syncthreads();
      // gather full h_t (16 rows x 256 cols) into LDS for next step.
      // Relaxed agent loads read the LLC directly — no stale-L2 hazard.
#pragma unroll
      for (int i2 = 0; i2 < 4; ++i2) {
        int flat = tid * 4 + i2;
        int pm = flat >> 6, cu = flat & 63;
        ull v = __hip_atomic_load(&hbuf[((long)(par * 16 + g) * 16 + pm) * 64 + cu],
                                  __ATOMIC_RELAXED, __HIP_MEMORY_SCOPE_AGENT);
        *(ull*)(&h_lds[pm][cu * 4]) = v;
      }
      __syncthreads();
    }
  }
}

// ---------------------------------------------------------------------------
// K4: projection  out1[M=131072][702] = hs16[M][256] @ Wrec16^T + b_rec
// Grid 8192 = 2048 M-blocks (tile 64) x 4 N-blocks (tile 192). Wave w handles
// n-tiles {3w..3w+2}; B-fragments in registers, A staged in LDS.
__global__ void __launch_bounds__(256) k_proj(const char* ws, const void* brec,
                                              void* dout, const int* dtf) {
  const int bf  = *dtf;
  const int tid = threadIdx.x;
  const int wid = tid >> 6, lane = tid & 63, q = lane >> 4, r = lane & 15;
  const int mb = blockIdx.x & 2047, nb = blockIdx.x >> 11;
  const long mbase = (long)mb * 64;
  const int  nbase = nb * 192;
  const _Float16* hs16 = (const _Float16*)(ws + OFF_HS16);
  const _Float16* wr16 = (const _Float16*)(ws + OFF_WREC16);

  __shared__ _Float16 a_lds[64][264];
#pragma unroll
  for (int i = 0; i < 8; ++i) {
    int u = tid + i * 256;              // 2048 units of 8 halves
    int row = u >> 5, c8 = (u & 31) * 8;
    half8 v = *(const half8*)(hs16 + (mbase + row) * H_ + c8);
    *(half8*)(&a_lds[row][c8]) = v;
  }
  __syncthreads();

  half8 bfrag[3][8];
  float bias[3];
#pragma unroll
  for (int j = 0; j < 3; ++j) {
    int ncol = nbase + (wid * 3 + j) * 16 + r;
    bias[j] = 0.0f;
    if (ncol < 704) {
      const long wrow = (long)ncol * H_;
#pragma unroll
      for (int kb = 0; kb < 8; ++kb)
        bfrag[j][kb] = *(const half8*)(wr16 + wrow + kb * 32 + q * 8);
    } else {
      half8 z = {0, 0, 0, 0, 0, 0, 0, 0};
#pragma unroll
      for (int kb = 0; kb < 8; ++kb) bfrag[j][kb] = z;
    }
    if (ncol < OUT_) bias[j] = ldin(brec, ncol, bf);
  }

  floatx4 acc[3][4];
#pragma unroll
  for (int j = 0; j < 3; ++j)
#pragma unroll
    for (int ms = 0; ms < 4; ++ms) acc[j][ms] = (floatx4){0.f, 0.f, 0.f, 0.f};

#pragma unroll
  for (int ms = 0; ms < 4; ++ms) {
#pragma unroll
    for (int kb = 0; kb < 8; ++kb) {
      half8 a = *(const half8*)(&a_lds[ms * 16 + r][kb * 32 + q * 8]);
#pragma unroll
      for (int j = 0; j < 3; ++j)
        acc[j][ms] = __builtin_amdgcn_mfma_f32_16x16x32_f16(a, bfrag[j][kb], acc[j][ms], 0, 0, 0);
    }
  }

#pragma unroll
  for (int j = 0; j < 3; ++j) {
    int ncol = nbase + (wid * 3 + j) * 16 + r;
    if (ncol >= OUT_) continue;
#pragma unroll
    for (int ms = 0; ms < 4; ++ms) {
#pragma unroll
      for (int e = 0; e < 4; ++e) {
        long mrow = mbase + ms * 16 + q * 4 + e;
        stout(dout, mrow * (long)OUT_ + ncol, acc[j][ms][e] + bias[j], bf);
      }
    }
  }
}

// ---------------------------------------------------------------------------
extern "C" void kernel_launch(void* const* d_in, const int* in_sizes, int n_in,
                              void* d_out, int out_size, void* d_ws, size_t ws_size,
                              hipStream_t stream) {
  const void* embed = d_in[0];
  const void* W_ih  = d_in[1];
  const void* W_hh  = d_in[2];
  const void* b_ih  = d_in[3];
  const void* b_hh  = d_in[4];
  const void* W_rec = d_in[5];
  const void* b_rec = d_in[6];
  char* ws = (char*)d_ws;
  const int* dtf = (const int*)(ws + OFF_DTF);

  // zero sync flags (+dtf slot) every launch — replay-safe
  hipMemsetAsync(ws, 0, 4096, stream);
  k_detect<<<1, 64, 0, stream>>>((const unsigned int*)embed, (int*)(ws + OFF_DTF));
  k_prep_wc<<<1024, 256, 0, stream>>>(W_ih, W_hh, (_Float16*)(ws + OFF_WC16), dtf);
  k_prep_wrec<<<704, 256, 0, stream>>>(W_rec, (_Float16*)(ws + OFF_WREC16), dtf);
  k_prep_base<<<1024, 256, 0, stream>>>(embed, W_ih, b_ih, b_hh, (float*)(ws + OFF_BASE), dtf);
  k_lstm<<<256, 256, 0, stream>>>(ws, d_out, dtf);
  k_proj<<<8192, 256, 0, stream>>>(ws, b_rec, d_out, dtf);
}